// Round 1
// baseline (456.437 us; speedup 1.0000x reference)
//
#include <hip/hip_runtime.h>
#include <stdint.h>

// Bitwise NAND/NOR bipartite layer:
//   out[i] = ~( nor_mask[i] ? (A[idx[i,0]] | A[idx[i,1]])
//                           : (A[idx[i,0]] & A[idx[i,1]]) )
// A: [32768 x 2048] int32.  Memory-bound gather+bitop.
//
// R1: persistent grid-stride blocks (4096), 2 rows per iteration with all 8
// gather loads issued before any store (128 B/lane in flight, 2x previous
// MLP). Format-detection prologue now runs 4096x instead of 32768x.

typedef int int4v __attribute__((ext_vector_type(4)));

#define NUM_WORDS 2048                 // int32 words per row
#define VECS_PER_ROW (NUM_WORDS / 4)   // 512 int4 per row
#define BLOCK 256
#define ROWS_PER_ITER 2
#define GRID_BLOCKS 4096               // 16 blocks/CU queued; 4 pair-iters each

__device__ __forceinline__ void load_idx(const void* idx_raw, bool idx_is_i64,
                                         long row, long& i0, long& i1) {
    if (idx_is_i64) {
        const long long* ip = (const long long*)idx_raw;
        i0 = (long)ip[2 * row];
        i1 = (long)ip[2 * row + 1];
    } else {
        const int* ip = (const int*)idx_raw;
        i0 = ip[2 * row];
        i1 = ip[2 * row + 1];
    }
}

__global__ __launch_bounds__(BLOCK) void nand_layer_kernel(
    const int4v* __restrict__ in_bits,   // [num_inputs * VECS_PER_ROW]
    const void* __restrict__ idx_raw,    // int32[rows*2] or int64[rows*2]
    const void* __restrict__ mask_raw,   // int32[rows] or uint8[rows]
    int4v* __restrict__ out,             // [rows * VECS_PER_ROW]
    int rows)
{
    // ---- representation detection (wave-uniform; compiles to s_loads) ----
    // nor_mask: int32 (values 0/1 -> upper bits always 0) vs byte-packed bool
    // (4 random 0/1 bytes per word -> upper-byte bits set with prob 7/8/word).
    const uint32_t* mw = (const uint32_t*)mask_raw;
    bool mask_is_i32 = true;
    #pragma unroll
    for (int i = 0; i < 32; ++i) {
        if (mw[i] & ~1u) mask_is_i32 = false;
    }
    // indices: int64 layout has all odd 32-bit words == 0 (values < 2^15);
    // int32 layout has random values in [0,32768) at odd words.
    const uint32_t* iw = (const uint32_t*)idx_raw;
    bool idx_is_i64 = true;
    #pragma unroll
    for (int i = 0; i < 16; ++i) {
        if (iw[2 * i + 1] != 0u) idx_is_i64 = false;
    }

    const int t = threadIdx.x;
    const long stride = (long)gridDim.x * ROWS_PER_ITER;

    for (long r = (long)blockIdx.x * ROWS_PER_ITER; r < rows; r += stride) {
        const bool have2 = (r + 1 < (long)rows);

        long i00, i01, i10 = 0, i11 = 0;
        load_idx(idx_raw, idx_is_i64, r, i00, i01);
        if (have2) load_idx(idx_raw, idx_is_i64, r + 1, i10, i11);

        bool nor0, nor1 = false;
        if (mask_is_i32) {
            nor0 = ((const int*)mask_raw)[r] != 0;
            if (have2) nor1 = ((const int*)mask_raw)[r + 1] != 0;
        } else {
            nor0 = ((const uint8_t*)mask_raw)[r] != 0;
            if (have2) nor1 = ((const uint8_t*)mask_raw)[r + 1] != 0;
        }

        const int4v* __restrict__ a0 = in_bits + i00 * VECS_PER_ROW;
        const int4v* __restrict__ b0 = in_bits + i01 * VECS_PER_ROW;
        int4v* __restrict__ o0 = out + r * VECS_PER_ROW;

        if (have2) {
            const int4v* __restrict__ a1 = in_bits + i10 * VECS_PER_ROW;
            const int4v* __restrict__ b1 = in_bits + i11 * VECS_PER_ROW;
            int4v* __restrict__ o1 = out + (r + 1) * VECS_PER_ROW;

            // 8 independent 16B loads per lane, issued before any store.
            int4v av00 = a0[t];           int4v bv00 = b0[t];
            int4v av01 = a0[t + BLOCK];   int4v bv01 = b0[t + BLOCK];
            int4v av10 = a1[t];           int4v bv10 = b1[t];
            int4v av11 = a1[t + BLOCK];   int4v bv11 = b1[t + BLOCK];

            int4v r00 = nor0 ? ~(av00 | bv00) : ~(av00 & bv00);
            int4v r01 = nor0 ? ~(av01 | bv01) : ~(av01 & bv01);
            int4v r10 = nor1 ? ~(av10 | bv10) : ~(av10 & bv10);
            int4v r11 = nor1 ? ~(av11 | bv11) : ~(av11 & bv11);

            // output is write-once, never re-read: stream past L2/L3 so the
            // gathered input (256 MiB == L3 size) keeps the cache.
            __builtin_nontemporal_store(r00, &o0[t]);
            __builtin_nontemporal_store(r01, &o0[t + BLOCK]);
            __builtin_nontemporal_store(r10, &o1[t]);
            __builtin_nontemporal_store(r11, &o1[t + BLOCK]);
        } else {
            int4v av00 = a0[t];           int4v bv00 = b0[t];
            int4v av01 = a0[t + BLOCK];   int4v bv01 = b0[t + BLOCK];
            int4v r00 = nor0 ? ~(av00 | bv00) : ~(av00 & bv00);
            int4v r01 = nor0 ? ~(av01 | bv01) : ~(av01 & bv01);
            __builtin_nontemporal_store(r00, &o0[t]);
            __builtin_nontemporal_store(r01, &o0[t + BLOCK]);
        }
    }
}

extern "C" void kernel_launch(void* const* d_in, const int* in_sizes, int n_in,
                              void* d_out, int out_size, void* d_ws, size_t ws_size,
                              hipStream_t stream) {
    (void)n_in; (void)d_ws; (void)ws_size; (void)out_size;
    const int rows = in_sizes[2];                 // NUM_OUTPUTS (nor_mask count)
    const int4v* in_bits = (const int4v*)d_in[0];
    const void* idx_raw  = d_in[1];
    const void* mask_raw = d_in[2];
    int4v* out = (int4v*)d_out;

    int grid = GRID_BLOCKS;
    const int need = (rows + ROWS_PER_ITER - 1) / ROWS_PER_ITER;
    if (grid > need) grid = need;

    nand_layer_kernel<<<grid, BLOCK, 0, stream>>>(in_bits, idx_raw, mask_raw,
                                                  out, rows);
}